// Round 9
// baseline (133.377 us; speedup 1.0000x reference)
//
#include <hip/hip_runtime.h>
#include <math.h>

#define NN 8192
#define CF 192
#define KNN 9
#define NSPL 8
#define PKS 12   // padded partial-list stride (16B-aligned for float4 preloads)

typedef __bf16 v8bf __attribute__((ext_vector_type(8)));
typedef float f32x16 __attribute__((ext_vector_type(16)));
typedef float f32x4 __attribute__((ext_vector_type(4)));

__device__ __forceinline__ int group_start(int g) {
    // smallest i with batch[i]==g :  ceil(8191*g/8), capped at 8192
    int s = (8191 * g + 7) >> 3;
    return s > 8192 ? 8192 : s;
}

__device__ __forceinline__ float disf(int d) {
    return d > 0 ? 1.0f / sqrtf((float)d) : 0.0f;
}

__device__ __forceinline__ unsigned short f2bf(float f) {
    unsigned u = __float_as_uint(f);
    unsigned r = (u + 0x7FFFu + ((u >> 16) & 1u)) >> 16;   // round-nearest-even
    return (unsigned short)r;
}
__device__ __forceinline__ float bf2f(unsigned short h) {
    return __uint_as_float(((unsigned)h) << 16);
}

// ---------------------------------------------------------------- transpose + split + sq
// x [8,192,32,32] -> xh/xl [8192][192] bf16 (hi/lo split, computed once).
// R23: grid (8,32) — 256 blocks (was 128 = 0.5/CU, half the chip idle).
// Each block owns 32 nodes x 192 ch; per-block serial LDS chain halved.
__global__ __launch_bounds__(256) void transpose_kernel(
    const float* __restrict__ x, unsigned short* __restrict__ xh,
    unsigned short* __restrict__ xl, float* __restrict__ sq,
    int* __restrict__ deg)
{
    __shared__ float tile[32][33];
    int b = blockIdx.x, ht = blockIdx.y;         // 8 x 32 blocks
    int hw0 = ht * 32;
    int tid = threadIdx.x;
    if (tid < 32) deg[b * 1024 + hw0 + tid] = 0;

    float sacc[4];
#pragma unroll
    for (int p = 0; p < 4; ++p) sacc[p] = 0.0f;

    for (int ct = 0; ct < 6; ++ct) {
        int c0 = ct * 32;
        __syncthreads();
#pragma unroll
        for (int p = 0; p < 4; ++p) {
            int c  = p * 8 + (tid >> 5);
            int hw = tid & 31;
            tile[c][hw] = x[(size_t)b * 196608 + (size_t)(c0 + c) * 1024 + hw0 + hw];
        }
        __syncthreads();
#pragma unroll
        for (int p = 0; p < 4; ++p) {
            int hw = p * 8 + (tid >> 5);
            int cc = tid & 31;
            float v = tile[cc][hw];
            size_t o = (size_t)(b * 1024 + hw0 + hw) * CF + c0 + cc;
            unsigned short h = f2bf(v);
            xh[o] = h;
            xl[o] = f2bf(v - bf2f(h));
            sacc[p] = fmaf(v, v, sacc[p]);
        }
    }
#pragma unroll
    for (int p = 0; p < 4; ++p) {
        float s = sacc[p];
#pragma unroll
        for (int off = 16; off > 0; off >>= 1) s += __shfl_xor(s, off, 32);
        if ((tid & 31) == 0)
            sq[(size_t)(b * 1024 + hw0 + p * 8 + (tid >> 5))] = s;
    }
}

// ---------------------------------------------------------------- kNN partial (MFMA)
// grid: 9 groups x 16 query-blocks(64 q) x 8 candidate-splits(128 c) = 1152.
// R22 (verified passing): BK=64 K-loop — 3 rolling iters x 2 barriers.
// Staging: 6 role addresses x TWO NAMED uint4 (12 named regs, no arrays ->
// spill-proof). Row stride 72 shorts (144B): 16B-aligned ds ops, 4-way read
// alias, free writes. LDS 55.3KB -> 2 blocks/CU (R19: TLP-insensitive).
// Selection/merge tail: R21 (verified -13us): contiguous chunk per lane-quad
// + 2-round __shfl_xor tree merge, stable tie order.
// C/D layout (HW-verified): col=lane&31, row=(reg&3)+8*(reg>>2)+4*(lane>>5).
__global__ __launch_bounds__(256, 2) void knn_kernel(
    const unsigned short* __restrict__ xh, const unsigned short* __restrict__ xl,
    const float* __restrict__ sq,
    float* __restrict__ pk_d, int* __restrict__ pk_i)
{
    int bid = blockIdx.x;
    int g = bid >> 7;
    int rem = bid & 127;
    int qb = rem >> 3;
    int split = rem & 7;
    int gs = group_start(g);
    int gsize = group_start(g + 1) - gs;
    int q0 = qb * 64;
    int nq = gsize - q0; if (nq > 64) nq = 64;
    if (nq <= 0) return;                 // block-uniform; q's covered elsewhere
    int c0 = split * 128;
    int ncc = gsize - c0; if (ncc > 128) ncc = 128;

    int tid = threadIdx.x;

    if (ncc <= 0) {                      // block-uniform: empty split
        if (tid < nq) {
            int q = gs + q0 + tid;
            size_t base = ((size_t)q * NSPL + split) * PKS;
#pragma unroll
            for (int j = 0; j < KNN; ++j) { pk_d[base + j] = __builtin_inff(); pk_i[base + j] = -1; }
        }
        return;
    }

    // staging 55296 B (BK=64, row 72 shorts) overlaid by Ds[64][133] (34048 B)
    // short-offsets: Ah[64][72] @0, Al @4608, Bh[128][72] @9216, Bl @18432
    __shared__ __align__(16) char smem[55296];
    unsigned short* sm = (unsigned short*)smem;
    __shared__ float sqc_s[128];
    __shared__ float sqq_s[64];

    int lane = tid & 63, w = tid >> 6;
    int arow = (w & 1) * 32 + (lane & 31);
    int k8 = (lane >> 5) * 8;
    int brow0 = (w >> 1) * 64 + (lane & 31);

    if (tid < 64) {
        int qo = q0 + tid; if (qo > gsize - 1) qo = gsize - 1;
        sqq_s[tid] = sq[gs + qo];
    }
    if (tid < 128) {
        sqc_s[tid] = (tid < ncc) ? sq[gs + c0 + tid] : __builtin_inff();
    }

    // ---- fixed staging roles (6 addresses, 32B each = 2 uint4 per role).
    // NOTE: xl MUST be contiguous after xh (g+NN*CF selects the lo plane).
    int rr = tid >> 2, q4 = tid & 3;                 // q4 covers 16-short cols
    int aq = q0 + rr; if (aq > gsize - 1) aq = gsize - 1;
    int cqA = c0 + rr;      if (cqA > gsize - 1) cqA = gsize - 1;
    int cqB = c0 + 64 + rr; if (cqB > gsize - 1) cqB = gsize - 1;
    int g0 = (gs + aq)  * CF + q4 * 16;          // xh (A hi)
    int g1 = g0 + NN * CF;                       // xl (A lo)
    int g2 = (gs + cqA) * CF + q4 * 16;          // xh (B hi, rows 0..63)
    int g3 = (gs + cqB) * CF + q4 * 16;          // xh (B hi, rows 64..127)
    int g4 = g2 + NN * CF;                       // xl
    int g5 = g3 + NN * CF;                       // xl
    int s0 = rr * 72 + q4 * 16;                  // A hi
    int s1 = s0 + 4608;                          // A lo
    int s2 = 9216 + rr * 72 + q4 * 16;           // B hi rows 0..63
    int s3 = s2 + 4608;                          // B hi rows 64..127
    int s4 = s2 + 9216;                          // B lo rows 0..63
    int s5 = s3 + 9216;                          // B lo rows 64..127

    f32x16 acc[2];
#pragma unroll
    for (int t = 0; t < 2; ++t)
#pragma unroll
        for (int r = 0; r < 16; ++r) acc[t][r] = 0.0f;

    // 12 NAMED prefetch regs (no arrays, no rotation -> no scratch)
    uint4 d0a, d0b, d1a, d1b, d2a, d2b, d3a, d3b, d4a, d4b, d5a, d5b;
    d0a = *(const uint4*)(xh + g0); d0b = *(const uint4*)(xh + g0 + 8);
    d1a = *(const uint4*)(xh + g1); d1b = *(const uint4*)(xh + g1 + 8);
    d2a = *(const uint4*)(xh + g2); d2b = *(const uint4*)(xh + g2 + 8);
    d3a = *(const uint4*)(xh + g3); d3b = *(const uint4*)(xh + g3 + 8);
    d4a = *(const uint4*)(xh + g4); d4b = *(const uint4*)(xh + g4 + 8);
    d5a = *(const uint4*)(xh + g5); d5b = *(const uint4*)(xh + g5 + 8);

    for (int kb = 0; kb < 3; ++kb) {     // rolling; 2 barriers per iter
        *(uint4*)(sm + s0) = d0a; *(uint4*)(sm + s0 + 8) = d0b;
        *(uint4*)(sm + s1) = d1a; *(uint4*)(sm + s1 + 8) = d1b;
        *(uint4*)(sm + s2) = d2a; *(uint4*)(sm + s2 + 8) = d2b;
        *(uint4*)(sm + s3) = d3a; *(uint4*)(sm + s3 + 8) = d3b;
        *(uint4*)(sm + s4) = d4a; *(uint4*)(sm + s4 + 8) = d4b;
        *(uint4*)(sm + s5) = d5a; *(uint4*)(sm + s5 + 8) = d5b;
        __syncthreads();                 // staging visible
        if (kb < 2) {                    // issue kb+1; hides under 24 MFMAs
            int o = (kb + 1) * 64;
            d0a = *(const uint4*)(xh + g0 + o); d0b = *(const uint4*)(xh + g0 + o + 8);
            d1a = *(const uint4*)(xh + g1 + o); d1b = *(const uint4*)(xh + g1 + o + 8);
            d2a = *(const uint4*)(xh + g2 + o); d2b = *(const uint4*)(xh + g2 + o + 8);
            d3a = *(const uint4*)(xh + g3 + o); d3b = *(const uint4*)(xh + g3 + o + 8);
            d4a = *(const uint4*)(xh + g4 + o); d4b = *(const uint4*)(xh + g4 + o + 8);
            d5a = *(const uint4*)(xh + g5 + o); d5b = *(const uint4*)(xh + g5 + o + 8);
        }
#pragma unroll
        for (int h = 0; h < 4; ++h) {    // four 16-k halves of the 64-k tile
            int ao = arow * 72 + h * 16 + k8;
            v8bf a_hi = *(const v8bf*)(sm + ao);
            v8bf a_lo = *(const v8bf*)(sm + 4608 + ao);
#pragma unroll
            for (int t = 0; t < 2; ++t) {
                int bo = 9216 + (brow0 + t * 32) * 72 + h * 16 + k8;
                v8bf b_hi = *(const v8bf*)(sm + bo);
                v8bf b_lo = *(const v8bf*)(sm + 9216 + bo);
                acc[t] = __builtin_amdgcn_mfma_f32_32x32x16_bf16(a_hi, b_hi, acc[t], 0, 0, 0);
                acc[t] = __builtin_amdgcn_mfma_f32_32x32x16_bf16(a_lo, b_hi, acc[t], 0, 0, 0);
                acc[t] = __builtin_amdgcn_mfma_f32_32x32x16_bf16(a_hi, b_lo, acc[t], 0, 0, 0);
            }
        }
        __syncthreads();                 // frag reads done -> next write safe
    }

    // ---- single full-Gram dump: Ds[64][133] (bank-conflict-free both ways)
    float (*Ds)[133] = (float(*)[133])smem;          // 34048 B
#pragma unroll
    for (int t = 0; t < 2; ++t)
#pragma unroll
        for (int r = 0; r < 16; ++r) {
            int row = (w & 1) * 32 + (r & 3) + 8 * (r >> 2) + 4 * (lane >> 5);
            int col = (w >> 1) * 64 + t * 32 + (lane & 31);
            Ds[row][col] = acc[t][r];
        }
    __syncthreads();

    // ---- selection: thread (q = tid>>2, ch = tid&3) scans its CONTIGUOUS
    // 32-cand chunk [ch*32, ch*32+32) ascending, 4 batches of 8.
    int qq = tid >> 2, ch = tid & 3;
    float sqqv = sqq_s[qq];
    float pd[KNN]; int pi[KNN];
#pragma unroll
    for (int j = 0; j < KNN; ++j) { pd[j] = __builtin_inff(); pi[j] = -1; }
#pragma unroll
    for (int qt = 0; qt < 4; ++qt) {
        float dv[8], cv[8];
#pragma unroll
        for (int j8 = 0; j8 < 8; ++j8) {
            int c = ch * 32 + qt * 8 + j8;
            dv[j8] = Ds[qq][c];
            cv[j8] = sqc_s[c];
        }
#pragma unroll
        for (int j8 = 0; j8 < 8; ++j8) {
            float d = (sqqv - 2.0f * dv[j8]) + cv[j8];        // inf pad
            if (d < pd[KNN - 1]) {
                pd[KNN - 1] = d; pi[KNN - 1] = gs + c0 + ch * 32 + qt * 8 + j8;
#pragma unroll
                for (int j = KNN - 1; j > 0; --j) {
                    if (pd[j] < pd[j - 1]) {
                        float tf = pd[j]; pd[j] = pd[j - 1]; pd[j - 1] = tf;
                        int tn = pi[j]; pi[j] = pi[j - 1]; pi[j - 1] = tn;
                    }
                }
            }
        }
    }

    // ---- intra-wave shuffle-tree merge: lanes 4q..4q+3 hold the 4 sorted
    // chunk-lists of query q. Two rounds (mask 1, then 2). Shuffles are
    // issued UNIFORMLY before the divergent insertion. Lower-ch list is
    // primary on ties (strict-< insert) -> index-order stable.
#define MERGE_ROUND(MASK, SELBIT)                                              \
    {                                                                          \
        float od[KNN]; int oi[KNN];                                            \
        _Pragma("unroll")                                                      \
        for (int j = 0; j < KNN; ++j) {                                        \
            od[j] = __shfl_xor(pd[j], MASK);                                   \
            oi[j] = __shfl_xor(pi[j], MASK);                                   \
        }                                                                      \
        bool swp = (ch & SELBIT) != 0;                                         \
        float ad[KNN]; int ai[KNN]; float bd[KNN]; int bi[KNN];                \
        _Pragma("unroll")                                                      \
        for (int j = 0; j < KNN; ++j) {                                        \
            ad[j] = swp ? od[j] : pd[j];  ai[j] = swp ? oi[j] : pi[j];         \
            bd[j] = swp ? pd[j] : od[j];  bi[j] = swp ? pi[j] : oi[j];         \
        }                                                                      \
        _Pragma("unroll")                                                      \
        for (int j0 = 0; j0 < KNN; ++j0) {                                     \
            float d = bd[j0];                                                  \
            if (!(d < ad[KNN - 1])) break;   /* sorted: rest can't insert */   \
            ad[KNN - 1] = d; ai[KNN - 1] = bi[j0];                             \
            _Pragma("unroll")                                                  \
            for (int j = KNN - 1; j > 0; --j) {                                \
                if (ad[j] < ad[j - 1]) {                                       \
                    float tf = ad[j]; ad[j] = ad[j - 1]; ad[j - 1] = tf;       \
                    int tn = ai[j]; ai[j] = ai[j - 1]; ai[j - 1] = tn;         \
                }                                                              \
            }                                                                  \
        }                                                                      \
        _Pragma("unroll")                                                      \
        for (int j = 0; j < KNN; ++j) { pd[j] = ad[j]; pi[j] = ai[j]; }        \
    }
    MERGE_ROUND(1, 1)
    MERGE_ROUND(2, 2)
#undef MERGE_ROUND

    if (ch == 0 && qq < nq) {
        int q = gs + q0 + qq;
        size_t base = ((size_t)q * NSPL + split) * PKS;
#pragma unroll
        for (int j = 0; j < KNN; ++j) { pk_d[base + j] = pd[j]; pk_i[base + j] = pi[j]; }
    }
}

// ---------------------------------------------------------------- merge + deg + W-transpose
// blocks 0..127: merge partial lists (64 q each) — stride-12 padded lists,
// float4/int4 register preload, branch-local early-break merge.
// blocks 128..199: build bf16 W0^T/W1^T into the dead xl region.
__global__ __launch_bounds__(64) void merge_kernel(
    const float* __restrict__ pk_d, const int* __restrict__ pk_i,
    int* __restrict__ edges, int* __restrict__ deg,
    const float* __restrict__ W0, const float* __restrict__ W1,
    unsigned short* __restrict__ wt)
{
    __shared__ float wtile[32][33];
    int tid = threadIdx.x;
    if (blockIdx.x >= 128) {             // ---- W transpose path
        int wid = blockIdx.x - 128;      // 0..71
        int mat = wid / 36, rem2 = wid % 36;
        int k0 = (rem2 / 6) * 32, n0 = (rem2 % 6) * 32;
        const float* W = mat ? W1 : W0;
#pragma unroll
        for (int p = 0; p < 4; ++p) {
            int idx = p * 64 + tid;
            int k = idx >> 3, n4 = (idx & 7) * 4;
            *(float4*)&wtile[k][n4] =
                *(const float4*)(W + (size_t)(k0 + k) * CF + n0 + n4);
        }
        __syncthreads();
#pragma unroll
        for (int p = 0; p < 4; ++p) {
            int idx = p * 64 + tid;
            int n = idx >> 3, k4 = (idx & 7) * 4;
            ushort4 h;
            h.x = f2bf(wtile[k4 + 0][n]); h.y = f2bf(wtile[k4 + 1][n]);
            h.z = f2bf(wtile[k4 + 2][n]); h.w = f2bf(wtile[k4 + 3][n]);
            *(ushort4*)(wt + (size_t)mat * 36864 + (size_t)(n0 + n) * CF + k0 + k4) = h;
        }
        return;
    }
    int q = blockIdx.x * 64 + tid;
    float td[KNN]; int ti[KNN];
#pragma unroll
    for (int j = 0; j < KNN; ++j) { td[j] = __builtin_inff(); ti[j] = -1; }
#pragma unroll
    for (int sb = 0; sb < 2; ++sb) {     // 2 batches of 4 splits, reg-preloaded
        float sd[4][KNN]; int si[4][KNN];
#pragma unroll
        for (int s2 = 0; s2 < 4; ++s2) {
            int s = sb * 4 + s2;         // compile-time (sb,s2 unrolled)
            const float* pd = pk_d + ((size_t)q * NSPL + s) * PKS;
            const int*   pp = pk_i + ((size_t)q * NSPL + s) * PKS;
            float4 d0 = *(const float4*)pd;
            float4 d1 = *(const float4*)(pd + 4);
            sd[s2][0] = d0.x; sd[s2][1] = d0.y; sd[s2][2] = d0.z; sd[s2][3] = d0.w;
            sd[s2][4] = d1.x; sd[s2][5] = d1.y; sd[s2][6] = d1.z; sd[s2][7] = d1.w;
            sd[s2][8] = pd[8];
            int4 i0 = *(const int4*)pp;
            int4 i1 = *(const int4*)(pp + 4);
            si[s2][0] = i0.x; si[s2][1] = i0.y; si[s2][2] = i0.z; si[s2][3] = i0.w;
            si[s2][4] = i1.x; si[s2][5] = i1.y; si[s2][6] = i1.z; si[s2][7] = i1.w;
            si[s2][8] = pp[8];
        }
#pragma unroll
        for (int s2 = 0; s2 < 4; ++s2) { // split order = index order (stable)
#pragma unroll
            for (int j0 = 0; j0 < KNN; ++j0) {
                float d = sd[s2][j0];
                if (!(d < td[KNN - 1])) break;   // sorted: rest can't insert
                td[KNN - 1] = d; ti[KNN - 1] = si[s2][j0];
#pragma unroll
                for (int j = KNN - 1; j > 0; --j) {
                    if (td[j] < td[j - 1]) {
                        float tf = td[j]; td[j] = td[j - 1]; td[j - 1] = tf;
                        int tn = ti[j]; ti[j] = ti[j - 1]; ti[j - 1] = tn;
                    }
                }
            }
        }
    }
#pragma unroll
    for (int j = 0; j < KNN; ++j) {
        int id = ti[j];                   // -1 <=> invalid (d == inf)
        edges[q * KNN + j] = id;
        if (id >= 0 && id != q) atomicAdd(&deg[id], 1);
    }
}

// ---------------------------------------------------------------- fused Tx1 + out GEMM (MFMA)
// One block per 16-row stripe (512 blocks). out = A0@W0 + A1@W1 + bias via
// mfma_f32_16x16x32_bf16, K=384 fused. R23: W-staging re-shaped to the
// knn-R16-proven loop — kt0 W loads issued at kernel TOP (latency hides
// under A0-stage/coef/gather), per-iter {barrier; ds_write regs; barrier;
// issue kt+1 loads; frags+MFMA}. 6 NAMED uint4 W-regs (no arrays — R17's
// spill trap). Barrier count unchanged; W L2 latency off the critical path.
// C/D (m89-verified): col=lane&15, row=(lane>>4)*4+reg. Wave w: n-tiles 3w..3w+2.
__global__ __launch_bounds__(256, 2) void out_kernel(
    const unsigned short* __restrict__ xh, const unsigned short* __restrict__ wt,
    const int* __restrict__ edges, const int* __restrict__ deg,
    const float* __restrict__ bias, float* __restrict__ out)
{
    __shared__ __align__(16) unsigned short A0s[16][200];  // xf rows  (padded)
    __shared__ __align__(16) unsigned short A1s[16][200];  // Tx1 rows (padded)
    __shared__ unsigned short Wts[2][CF][32];   // W^T k-slice (24576 B)
    __shared__ float coef_s[16][KNN];
    __shared__ int   nb_s[16][KNN];
    unsigned short* wts = &Wts[0][0][0];

    int r0 = blockIdx.x * 16;
    int tid = threadIdx.x;

    // ---- W-staging roles (6 per thread, p=0..5): precompute global base +
    // LDS offset once; kt0 loads issued FIRST so L2 latency hides under the
    // A0 staging + coef + gather phases below.
    int wb0, wb1, wb2, wb3, wb4, wb5;    // global short-offsets (kt=0)
    int ws0, ws1, ws2, ws3, ws4, ws5;    // LDS short-offsets
#define WROLE(P, GB, SB)                                                       \
    {                                                                          \
        int f = (P) * 256 + tid;                                               \
        int mat = f / 768, n = (f % 768) / 4, k16 = (f % 4) * 8;               \
        GB = mat * 36864 + n * CF + k16;                                       \
        SB = mat * 6144 + n * 32 + k16;                                        \
    }
    WROLE(0, wb0, ws0) WROLE(1, wb1, ws1) WROLE(2, wb2, ws2)
    WROLE(3, wb3, ws3) WROLE(4, wb4, ws4) WROLE(5, wb5, ws5)
#undef WROLE
    uint4 wr0 = *(const uint4*)(wt + wb0);
    uint4 wr1 = *(const uint4*)(wt + wb1);
    uint4 wr2 = *(const uint4*)(wt + wb2);
    uint4 wr3 = *(const uint4*)(wt + wb3);
    uint4 wr4 = *(const uint4*)(wt + wb4);
    uint4 wr5 = *(const uint4*)(wt + wb5);

    // stage xf rows (bf16 copy): 16 x 24 uint4 = 384
    for (int t = tid; t < 384; t += 256) {
        int i = t / 24, c8 = (t % 24) * 8;
        *(uint4*)&A0s[i][c8] = *(const uint4*)(xh + (size_t)(r0 + i) * CF + c8);
    }
    // coefficients: one (row, edge) per thread
    if (tid < 16 * KNN) {
        int i = tid / KNN, j = tid % KNN;
        int q = r0 + i;
        int id = edges[q * KNN + j];
        float cf = 0.0f; int s = q;
        if (id >= 0 && id != q) { cf = -disf(deg[id]) * disf(deg[q]); s = id; }
        coef_s[i][j] = cf; nb_s[i][j] = s;
    }
    __syncthreads();
    // gather Tx1 rows: role = (i, 8-ch block) -> 384 roles, uint4 per neighbor
    for (int e = tid; e < 16 * CF / 8; e += 256) {
        int i = e / 24, c8 = (e % 24) * 8;
        float a[8];
#pragma unroll
        for (int j = 0; j < 8; ++j) a[j] = 0.0f;
#pragma unroll
        for (int t = 0; t < KNN; ++t) {
            float cf = coef_s[i][t];
            uint4 v = *(const uint4*)(xh + (size_t)nb_s[i][t] * CF + c8);
            const unsigned short* pv = (const unsigned short*)&v;
#pragma unroll
            for (int j = 0; j < 8; ++j) a[j] = fmaf(cf, bf2f(pv[j]), a[j]);
        }
        uint4 hv;
        hv.x = (unsigned)f2bf(a[0]) | ((unsigned)f2bf(a[1]) << 16);
        hv.y = (unsigned)f2bf(a[2]) | ((unsigned)f2bf(a[3]) << 16);
        hv.z = (unsigned)f2bf(a[4]) | ((unsigned)f2bf(a[5]) << 16);
        hv.w = (unsigned)f2bf(a[6]) | ((unsigned)f2bf(a[7]) << 16);
        *(uint4*)&A1s[i][c8] = hv;
    }

    int lane = tid & 63, w = tid >> 6;
    int m = lane & 15;                   // A row / B col index
    int kq = (lane >> 4) * 8;            // k offset within 32-slice
    f32x4 acc[3];
#pragma unroll
    for (int t = 0; t < 3; ++t)
#pragma unroll
        for (int r = 0; r < 4; ++r) acc[t][r] = 0.0f;

    for (int kt = 0; kt < 6; ++kt) {     // K=192 in 32-slices, both mats fused
        __syncthreads();                 // kt=0: gather done; else Wts consumed
        *(uint4*)(wts + ws0) = wr0;
        *(uint4*)(wts + ws1) = wr1;
        *(uint4*)(wts + ws2) = wr2;
        *(uint4*)(wts + ws3) = wr3;
        *(uint4*)(wts + ws4) = wr4;
        *(uint4*)(wts + ws5) = wr5;
        __syncthreads();                 // Wts (and kt0: A1s) visible
        if (kt < 5) {                    // issue kt+1; hides under MFMA phase
            int o = (kt + 1) * 32;
            wr0 = *(const uint4*)(wt + wb0 + o);
            wr1 = *(const uint4*)(wt + wb1 + o);
            wr2 = *(const uint4*)(wt + wb2 + o);
            wr3 = *(const uint4*)(wt + wb3 + o);
            wr4 = *(const uint4*)(wt + wb4 + o);
            wr5 = *(const uint4*)(wt + wb5 + o);
        }
        v8bf a0 = *(const v8bf*)&A0s[m][kt * 32 + kq];
        v8bf a1 = *(const v8bf*)&A1s[m][kt * 32 + kq];
#pragma unroll
        for (int t3 = 0; t3 < 3; ++t3) {
            int n0 = w * 48 + t3 * 16;
            v8bf w0 = *(const v8bf*)(wts + (n0 + m) * 32 + kq);
            v8bf w1 = *(const v8bf*)(wts + 6144 + (n0 + m) * 32 + kq);
            acc[t3] = __builtin_amdgcn_mfma_f32_16x16x32_bf16(a0, w0, acc[t3], 0, 0, 0);
            acc[t3] = __builtin_amdgcn_mfma_f32_16x16x32_bf16(a1, w1, acc[t3], 0, 0, 0);
        }
    }

    int col = lane & 15, rb = (lane >> 4) * 4;
#pragma unroll
    for (int t3 = 0; t3 < 3; ++t3) {
        int n0 = w * 48 + t3 * 16;
        float bv = bias[n0 + col];
#pragma unroll
        for (int r = 0; r < 4; ++r)
            out[(size_t)(r0 + rb + r) * CF + n0 + col] = acc[t3][r] + bv;
    }
}

// ---------------------------------------------------------------- launch
extern "C" void kernel_launch(void* const* d_in, const int* in_sizes, int n_in,
                              void* d_out, int out_size, void* d_ws, size_t ws_size,
                              hipStream_t stream)
{
    const float* x    = (const float*)d_in[0];
    const float* W0   = (const float*)d_in[1];
    const float* W1   = (const float*)d_in[2];
    const float* bias = (const float*)d_in[3];
    float* out = (float*)d_out;

    // Workspace: 6,651,904 B (known-safe total).
    char* ws = (char*)d_ws;
    unsigned short* xh = (unsigned short*)ws; ws += (size_t)NN * CF * 2;  // 3,145,728
    unsigned short* xl = (unsigned short*)ws; ws += (size_t)NN * CF * 2;  // 3,145,728  (contiguous after xh — knn relies on this)
    float* sq    = (float*)ws;  ws += (size_t)NN * 4;        //    32,768
    int*   deg   = (int*)ws;    ws += (size_t)NN * 4;        //    32,768
    int*   edges = (int*)ws;    ws += (size_t)NN * KNN * 4;  //   294,912

    // xl is dead after knn -> reuse its space for bf16 W0^T/W1^T (147 KB).
    unsigned short* wt = xl;

    // Partial top-k lists live in d_out (exactly 6.29 MB with PKS=12); d_out
    // is fully overwritten by out_kernel afterwards, every call.
    float* pk_d = out;                                        // NN*NSPL*PKS fl
    int*   pk_i = (int*)(out + (size_t)NN * NSPL * PKS);      // NN*NSPL*PKS int

    hipLaunchKernelGGL(transpose_kernel, dim3(8, 32), dim3(256), 0, stream,
                       x, xh, xl, sq, deg);
    hipLaunchKernelGGL(knn_kernel, dim3(1152), dim3(256), 0, stream,
                       xh, xl, sq, pk_d, pk_i);
    hipLaunchKernelGGL(merge_kernel, dim3(200), dim3(64), 0, stream,
                       pk_d, pk_i, edges, deg, W0, W1, wt);
    hipLaunchKernelGGL(out_kernel, dim3(512), dim3(256), 0, stream,
                       xh, wt, edges, deg, bias, out);
}

// Round 10
// 130.429 us; speedup vs baseline: 1.0226x; 1.0226x over previous
//
#include <hip/hip_runtime.h>
#include <math.h>

#define NN 8192
#define CF 192
#define KNN 9
#define NSPL 8
#define PKS 12   // padded partial-list stride (16B-aligned for float4 preloads)

typedef __bf16 v8bf __attribute__((ext_vector_type(8)));
typedef float f32x16 __attribute__((ext_vector_type(16)));
typedef float f32x4 __attribute__((ext_vector_type(4)));

__device__ __forceinline__ int group_start(int g) {
    // smallest i with batch[i]==g :  ceil(8191*g/8), capped at 8192
    int s = (8191 * g + 7) >> 3;
    return s > 8192 ? 8192 : s;
}

__device__ __forceinline__ float disf(int d) {
    return d > 0 ? 1.0f / sqrtf((float)d) : 0.0f;
}

__device__ __forceinline__ unsigned short f2bf(float f) {
    unsigned u = __float_as_uint(f);
    unsigned r = (u + 0x7FFFu + ((u >> 16) & 1u)) >> 16;   // round-nearest-even
    return (unsigned short)r;
}
__device__ __forceinline__ float bf2f(unsigned short h) {
    return __uint_as_float(((unsigned)h) << 16);
}

// ---------------------------------------------------------------- transpose + split + sq
// x [8,192,32,32] -> xh/xl [8192][192] bf16 (hi/lo split, computed once).
// R23: grid (8,32) — 256 blocks; each block 32 nodes x 192 ch.
__global__ __launch_bounds__(256) void transpose_kernel(
    const float* __restrict__ x, unsigned short* __restrict__ xh,
    unsigned short* __restrict__ xl, float* __restrict__ sq,
    int* __restrict__ deg)
{
    __shared__ float tile[32][33];
    int b = blockIdx.x, ht = blockIdx.y;         // 8 x 32 blocks
    int hw0 = ht * 32;
    int tid = threadIdx.x;
    if (tid < 32) deg[b * 1024 + hw0 + tid] = 0;

    float sacc[4];
#pragma unroll
    for (int p = 0; p < 4; ++p) sacc[p] = 0.0f;

    for (int ct = 0; ct < 6; ++ct) {
        int c0 = ct * 32;
        __syncthreads();
#pragma unroll
        for (int p = 0; p < 4; ++p) {
            int c  = p * 8 + (tid >> 5);
            int hw = tid & 31;
            tile[c][hw] = x[(size_t)b * 196608 + (size_t)(c0 + c) * 1024 + hw0 + hw];
        }
        __syncthreads();
#pragma unroll
        for (int p = 0; p < 4; ++p) {
            int hw = p * 8 + (tid >> 5);
            int cc = tid & 31;
            float v = tile[cc][hw];
            size_t o = (size_t)(b * 1024 + hw0 + hw) * CF + c0 + cc;
            unsigned short h = f2bf(v);
            xh[o] = h;
            xl[o] = f2bf(v - bf2f(h));
            sacc[p] = fmaf(v, v, sacc[p]);
        }
    }
#pragma unroll
    for (int p = 0; p < 4; ++p) {
        float s = sacc[p];
#pragma unroll
        for (int off = 16; off > 0; off >>= 1) s += __shfl_xor(s, off, 32);
        if ((tid & 31) == 0)
            sq[(size_t)(b * 1024 + hw0 + p * 8 + (tid >> 5))] = s;
    }
}

// ---------------------------------------------------------------- kNN partial (MFMA)
// R24: 128q x 128c blocks — grid 9 x 8 qb x 8 splits = 576. B-rows staged
// per query: 2.0 -> 1.0 (staging traffic + ds-write work + barrier-events
// per query halve; work-removal lever, not scheduling — R17/R19/R20 showed
// schedule tweaks lose). BK=32, 6 rolling iters x 2 barriers; 24 MFMA/wave
// per barrier-pair (= R22). Wave w owns A-row-tile w (32 rows) x all 4
// col-tiles; acc = 4x f32x16. Staging: 4 roles x TWO NAMED uint4 (8 regs,
// spill-proof), row pad 40 shorts. LDS 40KB staging, Ds[64][133] overlay;
// selection runs twice (row-half per pass, waves (w>>1)==h dump), each pass
// = R21-proven contiguous-chunk scan + 2-round __shfl_xor tree merge.
// 576 blocks = 2.25/CU (R19: TLP-insensitive).
// C/D layout (HW-verified): col=lane&31, row=(reg&3)+8*(reg>>2)+4*(lane>>5).
__global__ __launch_bounds__(256, 2) void knn_kernel(
    const unsigned short* __restrict__ xh, const unsigned short* __restrict__ xl,
    const float* __restrict__ sq,
    float* __restrict__ pk_d, int* __restrict__ pk_i)
{
    int bid = blockIdx.x;
    int g = bid >> 6;                    // 64 blocks per group
    int rem = bid & 63;
    int qb = rem >> 3;                   // 0..7 (128 q each)
    int split = rem & 7;
    int gs = group_start(g);
    int gsize = group_start(g + 1) - gs;
    int q0 = qb * 128;
    int nq = gsize - q0; if (nq > 128) nq = 128;
    if (nq <= 0) return;                 // block-uniform; q's covered elsewhere
    int c0 = split * 128;
    int ncc = gsize - c0; if (ncc > 128) ncc = 128;

    int tid = threadIdx.x;

    if (ncc <= 0) {                      // block-uniform: empty split
        if (tid < nq) {
            int q = gs + q0 + tid;
            size_t base = ((size_t)q * NSPL + split) * PKS;
#pragma unroll
            for (int j = 0; j < KNN; ++j) { pk_d[base + j] = __builtin_inff(); pk_i[base + j] = -1; }
        }
        return;
    }

    // staging 40960 B (BK=32, row 40 shorts) overlaid by Ds[64][133] (34048 B)
    // short-offsets: Ah[128][40] @0, Al @5120, Bh[128][40] @10240, Bl @15360
    __shared__ __align__(16) char smem[40960];
    unsigned short* sm = (unsigned short*)smem;
    __shared__ float sqc_s[128];
    __shared__ float sqq_s[128];

    int lane = tid & 63, w = tid >> 6;
    int arow = w * 32 + (lane & 31);     // this wave's A row (0..127)
    int k8 = (lane >> 5) * 8;

    if (tid < 128) {
        int qo = q0 + tid; if (qo > gsize - 1) qo = gsize - 1;
        sqq_s[tid] = sq[gs + qo];
        sqc_s[tid] = (tid < ncc) ? sq[gs + c0 + tid] : __builtin_inff();
    }

    // ---- fixed staging roles: (row rr = tid>>1, half = tid&1), 4 planes,
    // each role = 32B = 2 uint4. xl contiguous after xh (+NN*CF).
    int rr = tid >> 1, half = tid & 1;
    int aq = q0 + rr; if (aq > gsize - 1) aq = gsize - 1;
    int cq = c0 + rr; if (cq > gsize - 1) cq = gsize - 1;
    int gA = (gs + aq) * CF + half * 16;         // xh (A hi)
    int gL = gA + NN * CF;                       // xl (A lo)
    int gB = (gs + cq) * CF + half * 16;         // xh (B hi)
    int gC = gB + NN * CF;                       // xl (B lo)
    int sA = rr * 40 + half * 16;                // A hi
    int sL = sA + 5120;                          // A lo
    int sB = 10240 + rr * 40 + half * 16;        // B hi
    int sC = sB + 5120;                          // B lo

    f32x16 acc[4];
#pragma unroll
    for (int t = 0; t < 4; ++t)
#pragma unroll
        for (int r = 0; r < 16; ++r) acc[t][r] = 0.0f;

    // 8 NAMED prefetch regs (no arrays, no rotation -> no scratch)
    uint4 rA0, rA1, rL0, rL1, rB0, rB1, rC0, rC1;
    rA0 = *(const uint4*)(xh + gA); rA1 = *(const uint4*)(xh + gA + 8);
    rL0 = *(const uint4*)(xh + gL); rL1 = *(const uint4*)(xh + gL + 8);
    rB0 = *(const uint4*)(xh + gB); rB1 = *(const uint4*)(xh + gB + 8);
    rC0 = *(const uint4*)(xh + gC); rC1 = *(const uint4*)(xh + gC + 8);

    for (int kb = 0; kb < 6; ++kb) {     // rolling; 2 barriers per iter
        *(uint4*)(sm + sA) = rA0; *(uint4*)(sm + sA + 8) = rA1;
        *(uint4*)(sm + sL) = rL0; *(uint4*)(sm + sL + 8) = rL1;
        *(uint4*)(sm + sB) = rB0; *(uint4*)(sm + sB + 8) = rB1;
        *(uint4*)(sm + sC) = rC0; *(uint4*)(sm + sC + 8) = rC1;
        __syncthreads();                 // staging visible
        if (kb < 5) {                    // issue kb+1; hides under 24 MFMAs
            int o = (kb + 1) * 32;
            rA0 = *(const uint4*)(xh + gA + o); rA1 = *(const uint4*)(xh + gA + o + 8);
            rL0 = *(const uint4*)(xh + gL + o); rL1 = *(const uint4*)(xh + gL + o + 8);
            rB0 = *(const uint4*)(xh + gB + o); rB1 = *(const uint4*)(xh + gB + o + 8);
            rC0 = *(const uint4*)(xh + gC + o); rC1 = *(const uint4*)(xh + gC + o + 8);
        }
#pragma unroll
        for (int h = 0; h < 2; ++h) {    // two 16-k halves of the 32-k tile
            int ao = arow * 40 + h * 16 + k8;
            v8bf a_hi = *(const v8bf*)(sm + ao);
            v8bf a_lo = *(const v8bf*)(sm + 5120 + ao);
#pragma unroll
            for (int t = 0; t < 4; ++t) {
                int bo = 10240 + (t * 32 + (lane & 31)) * 40 + h * 16 + k8;
                v8bf b_hi = *(const v8bf*)(sm + bo);
                v8bf b_lo = *(const v8bf*)(sm + 5120 + bo);
                acc[t] = __builtin_amdgcn_mfma_f32_32x32x16_bf16(a_hi, b_hi, acc[t], 0, 0, 0);
                acc[t] = __builtin_amdgcn_mfma_f32_32x32x16_bf16(a_lo, b_hi, acc[t], 0, 0, 0);
                acc[t] = __builtin_amdgcn_mfma_f32_32x32x16_bf16(a_hi, b_lo, acc[t], 0, 0, 0);
            }
        }
        __syncthreads();                 // frag reads done -> next write safe
    }

    // ---- selection in two row-half passes. Pass h: waves with (w>>1)==h
    // dump their 64x128 Gram half into Ds[64][133], then ALL threads select
    // for queries h*64..h*64+63 (q=tid>>2, ch=tid&3, contiguous 32-cand
    // chunk) and shuffle-merge (R21-proven, tie-stable).
    float (*Ds)[133] = (float(*)[133])smem;          // 34048 B overlay
    int qq = tid >> 2, ch = tid & 3;
#pragma unroll
    for (int h = 0; h < 2; ++h) {
        __syncthreads();                 // staging / prev-pass Ds reads done
        if ((w >> 1) == h) {
#pragma unroll
            for (int t = 0; t < 4; ++t)
#pragma unroll
                for (int r = 0; r < 16; ++r) {
                    int row = (w & 1) * 32 + (r & 3) + 8 * (r >> 2) + 4 * (lane >> 5);
                    Ds[row][t * 32 + (lane & 31)] = acc[t][r];
                }
        }
        __syncthreads();

        float sqqv = sqq_s[h * 64 + qq];
        float pd[KNN]; int pi[KNN];
#pragma unroll
        for (int j = 0; j < KNN; ++j) { pd[j] = __builtin_inff(); pi[j] = -1; }
#pragma unroll
        for (int qt = 0; qt < 4; ++qt) {
            float dv[8], cv[8];
#pragma unroll
            for (int j8 = 0; j8 < 8; ++j8) {
                int c = ch * 32 + qt * 8 + j8;
                dv[j8] = Ds[qq][c];
                cv[j8] = sqc_s[c];
            }
#pragma unroll
            for (int j8 = 0; j8 < 8; ++j8) {
                float d = (sqqv - 2.0f * dv[j8]) + cv[j8];        // inf pad
                if (d < pd[KNN - 1]) {
                    pd[KNN - 1] = d; pi[KNN - 1] = gs + c0 + ch * 32 + qt * 8 + j8;
#pragma unroll
                    for (int j = KNN - 1; j > 0; --j) {
                        if (pd[j] < pd[j - 1]) {
                            float tf = pd[j]; pd[j] = pd[j - 1]; pd[j - 1] = tf;
                            int tn = pi[j]; pi[j] = pi[j - 1]; pi[j - 1] = tn;
                        }
                    }
                }
            }
        }

        // intra-wave shuffle-tree merge: lanes 4q..4q+3 hold the 4 sorted
        // chunk-lists. Shuffles issued uniformly BEFORE the divergent
        // insertion; lower-ch list primary on ties (strict-<) -> stable.
#define MERGE_ROUND(MASK, SELBIT)                                              \
        {                                                                      \
            float od[KNN]; int oi[KNN];                                        \
            _Pragma("unroll")                                                  \
            for (int j = 0; j < KNN; ++j) {                                    \
                od[j] = __shfl_xor(pd[j], MASK);                               \
                oi[j] = __shfl_xor(pi[j], MASK);                               \
            }                                                                  \
            bool swp = (ch & SELBIT) != 0;                                     \
            float ad[KNN]; int ai[KNN]; float bd[KNN]; int bi[KNN];            \
            _Pragma("unroll")                                                  \
            for (int j = 0; j < KNN; ++j) {                                    \
                ad[j] = swp ? od[j] : pd[j];  ai[j] = swp ? oi[j] : pi[j];     \
                bd[j] = swp ? pd[j] : od[j];  bi[j] = swp ? pi[j] : oi[j];     \
            }                                                                  \
            _Pragma("unroll")                                                  \
            for (int j0 = 0; j0 < KNN; ++j0) {                                 \
                float d = bd[j0];                                              \
                if (!(d < ad[KNN - 1])) break;                                 \
                ad[KNN - 1] = d; ai[KNN - 1] = bi[j0];                         \
                _Pragma("unroll")                                              \
                for (int j = KNN - 1; j > 0; --j) {                            \
                    if (ad[j] < ad[j - 1]) {                                   \
                        float tf = ad[j]; ad[j] = ad[j - 1]; ad[j - 1] = tf;   \
                        int tn = ai[j]; ai[j] = ai[j - 1]; ai[j - 1] = tn;     \
                    }                                                          \
                }                                                              \
            }                                                                  \
            _Pragma("unroll")                                                  \
            for (int j = 0; j < KNN; ++j) { pd[j] = ad[j]; pi[j] = ai[j]; }    \
        }
        MERGE_ROUND(1, 1)
        MERGE_ROUND(2, 2)
#undef MERGE_ROUND

        if (ch == 0 && h * 64 + qq < nq) {
            int q = gs + q0 + h * 64 + qq;
            size_t base = ((size_t)q * NSPL + split) * PKS;
#pragma unroll
            for (int j = 0; j < KNN; ++j) { pk_d[base + j] = pd[j]; pk_i[base + j] = pi[j]; }
        }
    }
}

// ---------------------------------------------------------------- merge + deg + W-transpose
// blocks 0..127: merge partial lists (64 q each) — stride-12 padded lists,
// float4/int4 register preload, branch-local early-break merge.
// blocks 128..199: build bf16 W0^T/W1^T into the dead xl region.
__global__ __launch_bounds__(64) void merge_kernel(
    const float* __restrict__ pk_d, const int* __restrict__ pk_i,
    int* __restrict__ edges, int* __restrict__ deg,
    const float* __restrict__ W0, const float* __restrict__ W1,
    unsigned short* __restrict__ wt)
{
    __shared__ float wtile[32][33];
    int tid = threadIdx.x;
    if (blockIdx.x >= 128) {             // ---- W transpose path
        int wid = blockIdx.x - 128;      // 0..71
        int mat = wid / 36, rem2 = wid % 36;
        int k0 = (rem2 / 6) * 32, n0 = (rem2 % 6) * 32;
        const float* W = mat ? W1 : W0;
#pragma unroll
        for (int p = 0; p < 4; ++p) {
            int idx = p * 64 + tid;
            int k = idx >> 3, n4 = (idx & 7) * 4;
            *(float4*)&wtile[k][n4] =
                *(const float4*)(W + (size_t)(k0 + k) * CF + n0 + n4);
        }
        __syncthreads();
#pragma unroll
        for (int p = 0; p < 4; ++p) {
            int idx = p * 64 + tid;
            int n = idx >> 3, k4 = (idx & 7) * 4;
            ushort4 h;
            h.x = f2bf(wtile[k4 + 0][n]); h.y = f2bf(wtile[k4 + 1][n]);
            h.z = f2bf(wtile[k4 + 2][n]); h.w = f2bf(wtile[k4 + 3][n]);
            *(ushort4*)(wt + (size_t)mat * 36864 + (size_t)(n0 + n) * CF + k0 + k4) = h;
        }
        return;
    }
    int q = blockIdx.x * 64 + tid;
    float td[KNN]; int ti[KNN];
#pragma unroll
    for (int j = 0; j < KNN; ++j) { td[j] = __builtin_inff(); ti[j] = -1; }
#pragma unroll
    for (int sb = 0; sb < 2; ++sb) {     // 2 batches of 4 splits, reg-preloaded
        float sd[4][KNN]; int si[4][KNN];
#pragma unroll
        for (int s2 = 0; s2 < 4; ++s2) {
            int s = sb * 4 + s2;         // compile-time (sb,s2 unrolled)
            const float* pd = pk_d + ((size_t)q * NSPL + s) * PKS;
            const int*   pp = pk_i + ((size_t)q * NSPL + s) * PKS;
            float4 d0 = *(const float4*)pd;
            float4 d1 = *(const float4*)(pd + 4);
            sd[s2][0] = d0.x; sd[s2][1] = d0.y; sd[s2][2] = d0.z; sd[s2][3] = d0.w;
            sd[s2][4] = d1.x; sd[s2][5] = d1.y; sd[s2][6] = d1.z; sd[s2][7] = d1.w;
            sd[s2][8] = pd[8];
            int4 i0 = *(const int4*)pp;
            int4 i1 = *(const int4*)(pp + 4);
            si[s2][0] = i0.x; si[s2][1] = i0.y; si[s2][2] = i0.z; si[s2][3] = i0.w;
            si[s2][4] = i1.x; si[s2][5] = i1.y; si[s2][6] = i1.z; si[s2][7] = i1.w;
            si[s2][8] = pp[8];
        }
#pragma unroll
        for (int s2 = 0; s2 < 4; ++s2) { // split order = index order (stable)
#pragma unroll
            for (int j0 = 0; j0 < KNN; ++j0) {
                float d = sd[s2][j0];
                if (!(d < td[KNN - 1])) break;   // sorted: rest can't insert
                td[KNN - 1] = d; ti[KNN - 1] = si[s2][j0];
#pragma unroll
                for (int j = KNN - 1; j > 0; --j) {
                    if (td[j] < td[j - 1]) {
                        float tf = td[j]; td[j] = td[j - 1]; td[j - 1] = tf;
                        int tn = ti[j]; ti[j] = ti[j - 1]; ti[j - 1] = tn;
                    }
                }
            }
        }
    }
#pragma unroll
    for (int j = 0; j < KNN; ++j) {
        int id = ti[j];                   // -1 <=> invalid (d == inf)
        edges[q * KNN + j] = id;
        if (id >= 0 && id != q) atomicAdd(&deg[id], 1);
    }
}

// ---------------------------------------------------------------- fused Tx1 + out GEMM (MFMA)
// One block per 16-row stripe (512 blocks). out = A0@W0 + A1@W1 + bias via
// mfma_f32_16x16x32_bf16, K=384 fused. R23: kt0 W loads issued at kernel
// top (hide under A0-stage/coef/gather); per-iter {barrier; ds_write regs;
// barrier; issue kt+1; frags+MFMA}. 6 NAMED uint4 W-regs.
// C/D (m89-verified): col=lane&15, row=(lane>>4)*4+reg. Wave w: n-tiles 3w..3w+2.
__global__ __launch_bounds__(256, 2) void out_kernel(
    const unsigned short* __restrict__ xh, const unsigned short* __restrict__ wt,
    const int* __restrict__ edges, const int* __restrict__ deg,
    const float* __restrict__ bias, float* __restrict__ out)
{
    __shared__ __align__(16) unsigned short A0s[16][200];  // xf rows  (padded)
    __shared__ __align__(16) unsigned short A1s[16][200];  // Tx1 rows (padded)
    __shared__ unsigned short Wts[2][CF][32];   // W^T k-slice (24576 B)
    __shared__ float coef_s[16][KNN];
    __shared__ int   nb_s[16][KNN];
    unsigned short* wts = &Wts[0][0][0];

    int r0 = blockIdx.x * 16;
    int tid = threadIdx.x;

    int wb0, wb1, wb2, wb3, wb4, wb5;    // global short-offsets (kt=0)
    int ws0, ws1, ws2, ws3, ws4, ws5;    // LDS short-offsets
#define WROLE(P, GB, SB)                                                       \
    {                                                                          \
        int f = (P) * 256 + tid;                                               \
        int mat = f / 768, n = (f % 768) / 4, k16 = (f % 4) * 8;               \
        GB = mat * 36864 + n * CF + k16;                                       \
        SB = mat * 6144 + n * 32 + k16;                                        \
    }
    WROLE(0, wb0, ws0) WROLE(1, wb1, ws1) WROLE(2, wb2, ws2)
    WROLE(3, wb3, ws3) WROLE(4, wb4, ws4) WROLE(5, wb5, ws5)
#undef WROLE
    uint4 wr0 = *(const uint4*)(wt + wb0);
    uint4 wr1 = *(const uint4*)(wt + wb1);
    uint4 wr2 = *(const uint4*)(wt + wb2);
    uint4 wr3 = *(const uint4*)(wt + wb3);
    uint4 wr4 = *(const uint4*)(wt + wb4);
    uint4 wr5 = *(const uint4*)(wt + wb5);

    // stage xf rows (bf16 copy): 16 x 24 uint4 = 384
    for (int t = tid; t < 384; t += 256) {
        int i = t / 24, c8 = (t % 24) * 8;
        *(uint4*)&A0s[i][c8] = *(const uint4*)(xh + (size_t)(r0 + i) * CF + c8);
    }
    // coefficients: one (row, edge) per thread
    if (tid < 16 * KNN) {
        int i = tid / KNN, j = tid % KNN;
        int q = r0 + i;
        int id = edges[q * KNN + j];
        float cf = 0.0f; int s = q;
        if (id >= 0 && id != q) { cf = -disf(deg[id]) * disf(deg[q]); s = id; }
        coef_s[i][j] = cf; nb_s[i][j] = s;
    }
    __syncthreads();
    // gather Tx1 rows: role = (i, 8-ch block) -> 384 roles, uint4 per neighbor
    for (int e = tid; e < 16 * CF / 8; e += 256) {
        int i = e / 24, c8 = (e % 24) * 8;
        float a[8];
#pragma unroll
        for (int j = 0; j < 8; ++j) a[j] = 0.0f;
#pragma unroll
        for (int t = 0; t < KNN; ++t) {
            float cf = coef_s[i][t];
            uint4 v = *(const uint4*)(xh + (size_t)nb_s[i][t] * CF + c8);
            const unsigned short* pv = (const unsigned short*)&v;
#pragma unroll
            for (int j = 0; j < 8; ++j) a[j] = fmaf(cf, bf2f(pv[j]), a[j]);
        }
        uint4 hv;
        hv.x = (unsigned)f2bf(a[0]) | ((unsigned)f2bf(a[1]) << 16);
        hv.y = (unsigned)f2bf(a[2]) | ((unsigned)f2bf(a[3]) << 16);
        hv.z = (unsigned)f2bf(a[4]) | ((unsigned)f2bf(a[5]) << 16);
        hv.w = (unsigned)f2bf(a[6]) | ((unsigned)f2bf(a[7]) << 16);
        *(uint4*)&A1s[i][c8] = hv;
    }

    int lane = tid & 63, w = tid >> 6;
    int m = lane & 15;                   // A row / B col index
    int kq = (lane >> 4) * 8;            // k offset within 32-slice
    f32x4 acc[3];
#pragma unroll
    for (int t = 0; t < 3; ++t)
#pragma unroll
        for (int r = 0; r < 4; ++r) acc[t][r] = 0.0f;

    for (int kt = 0; kt < 6; ++kt) {     // K=192 in 32-slices, both mats fused
        __syncthreads();                 // kt=0: gather done; else Wts consumed
        *(uint4*)(wts + ws0) = wr0;
        *(uint4*)(wts + ws1) = wr1;
        *(uint4*)(wts + ws2) = wr2;
        *(uint4*)(wts + ws3) = wr3;
        *(uint4*)(wts + ws4) = wr4;
        *(uint4*)(wts + ws5) = wr5;
        __syncthreads();                 // Wts (and kt0: A1s) visible
        if (kt < 5) {                    // issue kt+1; hides under MFMA phase
            int o = (kt + 1) * 32;
            wr0 = *(const uint4*)(wt + wb0 + o);
            wr1 = *(const uint4*)(wt + wb1 + o);
            wr2 = *(const uint4*)(wt + wb2 + o);
            wr3 = *(const uint4*)(wt + wb3 + o);
            wr4 = *(const uint4*)(wt + wb4 + o);
            wr5 = *(const uint4*)(wt + wb5 + o);
        }
        v8bf a0 = *(const v8bf*)&A0s[m][kt * 32 + kq];
        v8bf a1 = *(const v8bf*)&A1s[m][kt * 32 + kq];
#pragma unroll
        for (int t3 = 0; t3 < 3; ++t3) {
            int n0 = w * 48 + t3 * 16;
            v8bf w0 = *(const v8bf*)(wts + (n0 + m) * 32 + kq);
            v8bf w1 = *(const v8bf*)(wts + 6144 + (n0 + m) * 32 + kq);
            acc[t3] = __builtin_amdgcn_mfma_f32_16x16x32_bf16(a0, w0, acc[t3], 0, 0, 0);
            acc[t3] = __builtin_amdgcn_mfma_f32_16x16x32_bf16(a1, w1, acc[t3], 0, 0, 0);
        }
    }

    int col = lane & 15, rb = (lane >> 4) * 4;
#pragma unroll
    for (int t3 = 0; t3 < 3; ++t3) {
        int n0 = w * 48 + t3 * 16;
        float bv = bias[n0 + col];
#pragma unroll
        for (int r = 0; r < 4; ++r)
            out[(size_t)(r0 + rb + r) * CF + n0 + col] = acc[t3][r] + bv;
    }
}

// ---------------------------------------------------------------- launch
extern "C" void kernel_launch(void* const* d_in, const int* in_sizes, int n_in,
                              void* d_out, int out_size, void* d_ws, size_t ws_size,
                              hipStream_t stream)
{
    const float* x    = (const float*)d_in[0];
    const float* W0   = (const float*)d_in[1];
    const float* W1   = (const float*)d_in[2];
    const float* bias = (const float*)d_in[3];
    float* out = (float*)d_out;

    // Workspace: 6,651,904 B (known-safe total).
    char* ws = (char*)d_ws;
    unsigned short* xh = (unsigned short*)ws; ws += (size_t)NN * CF * 2;  // 3,145,728
    unsigned short* xl = (unsigned short*)ws; ws += (size_t)NN * CF * 2;  // 3,145,728  (contiguous after xh — knn relies on this)
    float* sq    = (float*)ws;  ws += (size_t)NN * 4;        //    32,768
    int*   deg   = (int*)ws;    ws += (size_t)NN * 4;        //    32,768
    int*   edges = (int*)ws;    ws += (size_t)NN * KNN * 4;  //   294,912

    // xl is dead after knn -> reuse its space for bf16 W0^T/W1^T (147 KB).
    unsigned short* wt = xl;

    // Partial top-k lists live in d_out (exactly 6.29 MB with PKS=12); d_out
    // is fully overwritten by out_kernel afterwards, every call.
    float* pk_d = out;                                        // NN*NSPL*PKS fl
    int*   pk_i = (int*)(out + (size_t)NN * NSPL * PKS);      // NN*NSPL*PKS int

    hipLaunchKernelGGL(transpose_kernel, dim3(8, 32), dim3(256), 0, stream,
                       x, xh, xl, sq, deg);
    hipLaunchKernelGGL(knn_kernel, dim3(576), dim3(256), 0, stream,
                       xh, xl, sq, pk_d, pk_i);
    hipLaunchKernelGGL(merge_kernel, dim3(200), dim3(64), 0, stream,
                       pk_d, pk_i, edges, deg, W0, W1, wt);
    hipLaunchKernelGGL(out_kernel, dim3(512), dim3(256), 0, stream,
                       xh, wt, edges, deg, bias, out);
}

// Round 11
// 128.475 us; speedup vs baseline: 1.0382x; 1.0152x over previous
//
#include <hip/hip_runtime.h>
#include <math.h>

#define NN 8192
#define CF 192
#define KNN 9
#define NSPL 8
#define PKS 12   // padded partial-list stride (16B-aligned for float4 preloads)

typedef __bf16 v8bf __attribute__((ext_vector_type(8)));
typedef float f32x16 __attribute__((ext_vector_type(16)));
typedef float f32x4 __attribute__((ext_vector_type(4)));

__device__ __forceinline__ int group_start(int g) {
    // smallest i with batch[i]==g :  ceil(8191*g/8), capped at 8192
    int s = (8191 * g + 7) >> 3;
    return s > 8192 ? 8192 : s;
}

__device__ __forceinline__ float disf(int d) {
    return d > 0 ? 1.0f / sqrtf((float)d) : 0.0f;
}

__device__ __forceinline__ unsigned short f2bf(float f) {
    unsigned u = __float_as_uint(f);
    unsigned r = (u + 0x7FFFu + ((u >> 16) & 1u)) >> 16;   // round-nearest-even
    return (unsigned short)r;
}
__device__ __forceinline__ float bf2f(unsigned short h) {
    return __uint_as_float(((unsigned)h) << 16);
}

// ---------------------------------------------------------------- transpose + split + sq
// x [8,192,32,32] -> xh/xl [8192][192] bf16 (hi/lo split, computed once).
// R16/R18-proven form (present in both best-total runs 121.7/124.8):
// grid (8,16), one block owns 64 nodes x all 192 ch; sq local; deg zeroed.
__global__ __launch_bounds__(256) void transpose_kernel(
    const float* __restrict__ x, unsigned short* __restrict__ xh,
    unsigned short* __restrict__ xl, float* __restrict__ sq,
    int* __restrict__ deg)
{
    __shared__ float tile[32][65];
    int b = blockIdx.x, ht = blockIdx.y;         // 8 x 16 blocks
    int hw0 = ht * 64;
    int tid = threadIdx.x;
    if (tid < 64) deg[(b * 16 + ht) * 64 + tid] = 0;

    float sacc[8];
#pragma unroll
    for (int p = 0; p < 8; ++p) sacc[p] = 0.0f;

    for (int ct = 0; ct < 6; ++ct) {
        int c0 = ct * 32;
        __syncthreads();
#pragma unroll
        for (int p = 0; p < 8; ++p) {
            int c  = p * 4 + (tid >> 6);
            int hw = tid & 63;
            tile[c][hw] = x[(size_t)b * 196608 + (size_t)(c0 + c) * 1024 + hw0 + hw];
        }
        __syncthreads();
#pragma unroll
        for (int p = 0; p < 8; ++p) {
            int hw = p * 8 + (tid >> 5);
            int cc = tid & 31;
            float v = tile[cc][hw];
            size_t o = (size_t)(b * 1024 + hw0 + hw) * CF + c0 + cc;
            unsigned short h = f2bf(v);
            xh[o] = h;
            xl[o] = f2bf(v - bf2f(h));
            sacc[p] = fmaf(v, v, sacc[p]);
        }
    }
#pragma unroll
    for (int p = 0; p < 8; ++p) {
        float s = sacc[p];
#pragma unroll
        for (int off = 16; off > 0; off >>= 1) s += __shfl_xor(s, off, 32);
        if ((tid & 31) == 0)
            sq[(size_t)(b * 1024 + hw0 + p * 8 + (tid >> 5))] = s;
    }
}

// ---------------------------------------------------------------- kNN partial (MFMA)
// R24 (verified passing, best per-dispatch knn): 128q x 128c blocks — grid
// 9 x 8 qb x 8 splits = 576. B-rows staged per query 2.0 -> 1.0. BK=32,
// 6 rolling iters x 2 barriers; wave w owns A-row-tile w x all 4 col-tiles;
// acc = 4x f32x16. Staging: 4 roles x TWO NAMED uint4 (8 regs, spill-proof),
// row pad 40 shorts. LDS 40KB staging, Ds[64][133] overlay; selection in two
// row-half passes, each = R21-proven contiguous-chunk scan + 2-round
// __shfl_xor tree merge (tie-stable).
// C/D layout (HW-verified): col=lane&31, row=(reg&3)+8*(reg>>2)+4*(lane>>5).
__global__ __launch_bounds__(256, 2) void knn_kernel(
    const unsigned short* __restrict__ xh, const unsigned short* __restrict__ xl,
    const float* __restrict__ sq,
    float* __restrict__ pk_d, int* __restrict__ pk_i)
{
    int bid = blockIdx.x;
    int g = bid >> 6;                    // 64 blocks per group
    int rem = bid & 63;
    int qb = rem >> 3;                   // 0..7 (128 q each)
    int split = rem & 7;
    int gs = group_start(g);
    int gsize = group_start(g + 1) - gs;
    int q0 = qb * 128;
    int nq = gsize - q0; if (nq > 128) nq = 128;
    if (nq <= 0) return;                 // block-uniform; q's covered elsewhere
    int c0 = split * 128;
    int ncc = gsize - c0; if (ncc > 128) ncc = 128;

    int tid = threadIdx.x;

    if (ncc <= 0) {                      // block-uniform: empty split
        if (tid < nq) {
            int q = gs + q0 + tid;
            size_t base = ((size_t)q * NSPL + split) * PKS;
#pragma unroll
            for (int j = 0; j < KNN; ++j) { pk_d[base + j] = __builtin_inff(); pk_i[base + j] = -1; }
        }
        return;
    }

    // staging 40960 B (BK=32, row 40 shorts) overlaid by Ds[64][133] (34048 B)
    // short-offsets: Ah[128][40] @0, Al @5120, Bh[128][40] @10240, Bl @15360
    __shared__ __align__(16) char smem[40960];
    unsigned short* sm = (unsigned short*)smem;
    __shared__ float sqc_s[128];
    __shared__ float sqq_s[128];

    int lane = tid & 63, w = tid >> 6;
    int arow = w * 32 + (lane & 31);     // this wave's A row (0..127)
    int k8 = (lane >> 5) * 8;

    if (tid < 128) {
        int qo = q0 + tid; if (qo > gsize - 1) qo = gsize - 1;
        sqq_s[tid] = sq[gs + qo];
        sqc_s[tid] = (tid < ncc) ? sq[gs + c0 + tid] : __builtin_inff();
    }

    // ---- fixed staging roles: (row rr = tid>>1, half = tid&1), 4 planes,
    // each role = 32B = 2 uint4. xl contiguous after xh (+NN*CF).
    int rr = tid >> 1, half = tid & 1;
    int aq = q0 + rr; if (aq > gsize - 1) aq = gsize - 1;
    int cq = c0 + rr; if (cq > gsize - 1) cq = gsize - 1;
    int gA = (gs + aq) * CF + half * 16;         // xh (A hi)
    int gL = gA + NN * CF;                       // xl (A lo)
    int gB = (gs + cq) * CF + half * 16;         // xh (B hi)
    int gC = gB + NN * CF;                       // xl (B lo)
    int sA = rr * 40 + half * 16;                // A hi
    int sL = sA + 5120;                          // A lo
    int sB = 10240 + rr * 40 + half * 16;        // B hi
    int sC = sB + 5120;                          // B lo

    f32x16 acc[4];
#pragma unroll
    for (int t = 0; t < 4; ++t)
#pragma unroll
        for (int r = 0; r < 16; ++r) acc[t][r] = 0.0f;

    // 8 NAMED prefetch regs (no arrays, no rotation -> no scratch)
    uint4 rA0, rA1, rL0, rL1, rB0, rB1, rC0, rC1;
    rA0 = *(const uint4*)(xh + gA); rA1 = *(const uint4*)(xh + gA + 8);
    rL0 = *(const uint4*)(xh + gL); rL1 = *(const uint4*)(xh + gL + 8);
    rB0 = *(const uint4*)(xh + gB); rB1 = *(const uint4*)(xh + gB + 8);
    rC0 = *(const uint4*)(xh + gC); rC1 = *(const uint4*)(xh + gC + 8);

    for (int kb = 0; kb < 6; ++kb) {     // rolling; 2 barriers per iter
        *(uint4*)(sm + sA) = rA0; *(uint4*)(sm + sA + 8) = rA1;
        *(uint4*)(sm + sL) = rL0; *(uint4*)(sm + sL + 8) = rL1;
        *(uint4*)(sm + sB) = rB0; *(uint4*)(sm + sB + 8) = rB1;
        *(uint4*)(sm + sC) = rC0; *(uint4*)(sm + sC + 8) = rC1;
        __syncthreads();                 // staging visible
        if (kb < 5) {                    // issue kb+1; hides under 24 MFMAs
            int o = (kb + 1) * 32;
            rA0 = *(const uint4*)(xh + gA + o); rA1 = *(const uint4*)(xh + gA + o + 8);
            rL0 = *(const uint4*)(xh + gL + o); rL1 = *(const uint4*)(xh + gL + o + 8);
            rB0 = *(const uint4*)(xh + gB + o); rB1 = *(const uint4*)(xh + gB + o + 8);
            rC0 = *(const uint4*)(xh + gC + o); rC1 = *(const uint4*)(xh + gC + o + 8);
        }
#pragma unroll
        for (int h = 0; h < 2; ++h) {    // two 16-k halves of the 32-k tile
            int ao = arow * 40 + h * 16 + k8;
            v8bf a_hi = *(const v8bf*)(sm + ao);
            v8bf a_lo = *(const v8bf*)(sm + 5120 + ao);
#pragma unroll
            for (int t = 0; t < 4; ++t) {
                int bo = 10240 + (t * 32 + (lane & 31)) * 40 + h * 16 + k8;
                v8bf b_hi = *(const v8bf*)(sm + bo);
                v8bf b_lo = *(const v8bf*)(sm + 5120 + bo);
                acc[t] = __builtin_amdgcn_mfma_f32_32x32x16_bf16(a_hi, b_hi, acc[t], 0, 0, 0);
                acc[t] = __builtin_amdgcn_mfma_f32_32x32x16_bf16(a_lo, b_hi, acc[t], 0, 0, 0);
                acc[t] = __builtin_amdgcn_mfma_f32_32x32x16_bf16(a_hi, b_lo, acc[t], 0, 0, 0);
            }
        }
        __syncthreads();                 // frag reads done -> next write safe
    }

    // ---- selection in two row-half passes. Pass h: waves with (w>>1)==h
    // dump their 64x128 Gram half into Ds[64][133], then ALL threads select
    // for queries h*64..h*64+63 (q=tid>>2, ch=tid&3, contiguous 32-cand
    // chunk) and shuffle-merge (R21-proven, tie-stable).
    float (*Ds)[133] = (float(*)[133])smem;          // 34048 B overlay
    int qq = tid >> 2, ch = tid & 3;
#pragma unroll
    for (int h = 0; h < 2; ++h) {
        __syncthreads();                 // staging / prev-pass Ds reads done
        if ((w >> 1) == h) {
#pragma unroll
            for (int t = 0; t < 4; ++t)
#pragma unroll
                for (int r = 0; r < 16; ++r) {
                    int row = (w & 1) * 32 + (r & 3) + 8 * (r >> 2) + 4 * (lane >> 5);
                    Ds[row][t * 32 + (lane & 31)] = acc[t][r];
                }
        }
        __syncthreads();

        float sqqv = sqq_s[h * 64 + qq];
        float pd[KNN]; int pi[KNN];
#pragma unroll
        for (int j = 0; j < KNN; ++j) { pd[j] = __builtin_inff(); pi[j] = -1; }
#pragma unroll
        for (int qt = 0; qt < 4; ++qt) {
            float dv[8], cv[8];
#pragma unroll
            for (int j8 = 0; j8 < 8; ++j8) {
                int c = ch * 32 + qt * 8 + j8;
                dv[j8] = Ds[qq][c];
                cv[j8] = sqc_s[c];
            }
#pragma unroll
            for (int j8 = 0; j8 < 8; ++j8) {
                float d = (sqqv - 2.0f * dv[j8]) + cv[j8];        // inf pad
                if (d < pd[KNN - 1]) {
                    pd[KNN - 1] = d; pi[KNN - 1] = gs + c0 + ch * 32 + qt * 8 + j8;
#pragma unroll
                    for (int j = KNN - 1; j > 0; --j) {
                        if (pd[j] < pd[j - 1]) {
                            float tf = pd[j]; pd[j] = pd[j - 1]; pd[j - 1] = tf;
                            int tn = pi[j]; pi[j] = pi[j - 1]; pi[j - 1] = tn;
                        }
                    }
                }
            }
        }

        // intra-wave shuffle-tree merge: lanes 4q..4q+3 hold the 4 sorted
        // chunk-lists. Shuffles issued uniformly BEFORE the divergent
        // insertion; lower-ch list primary on ties (strict-<) -> stable.
#define MERGE_ROUND(MASK, SELBIT)                                              \
        {                                                                      \
            float od[KNN]; int oi[KNN];                                        \
            _Pragma("unroll")                                                  \
            for (int j = 0; j < KNN; ++j) {                                    \
                od[j] = __shfl_xor(pd[j], MASK);                               \
                oi[j] = __shfl_xor(pi[j], MASK);                               \
            }                                                                  \
            bool swp = (ch & SELBIT) != 0;                                     \
            float ad[KNN]; int ai[KNN]; float bd[KNN]; int bi[KNN];            \
            _Pragma("unroll")                                                  \
            for (int j = 0; j < KNN; ++j) {                                    \
                ad[j] = swp ? od[j] : pd[j];  ai[j] = swp ? oi[j] : pi[j];     \
                bd[j] = swp ? pd[j] : od[j];  bi[j] = swp ? pi[j] : oi[j];     \
            }                                                                  \
            _Pragma("unroll")                                                  \
            for (int j0 = 0; j0 < KNN; ++j0) {                                 \
                float d = bd[j0];                                              \
                if (!(d < ad[KNN - 1])) break;                                 \
                ad[KNN - 1] = d; ai[KNN - 1] = bi[j0];                         \
                _Pragma("unroll")                                              \
                for (int j = KNN - 1; j > 0; --j) {                            \
                    if (ad[j] < ad[j - 1]) {                                   \
                        float tf = ad[j]; ad[j] = ad[j - 1]; ad[j - 1] = tf;   \
                        int tn = ai[j]; ai[j] = ai[j - 1]; ai[j - 1] = tn;     \
                    }                                                          \
                }                                                              \
            }                                                                  \
            _Pragma("unroll")                                                  \
            for (int j = 0; j < KNN; ++j) { pd[j] = ad[j]; pi[j] = ai[j]; }    \
        }
        MERGE_ROUND(1, 1)
        MERGE_ROUND(2, 2)
#undef MERGE_ROUND

        if (ch == 0 && h * 64 + qq < nq) {
            int q = gs + q0 + h * 64 + qq;
            size_t base = ((size_t)q * NSPL + split) * PKS;
#pragma unroll
            for (int j = 0; j < KNN; ++j) { pk_d[base + j] = pd[j]; pk_i[base + j] = pi[j]; }
        }
    }
}

// ---------------------------------------------------------------- merge + deg + W-transpose
// blocks 0..127: merge partial lists (64 q each) — stride-12 padded lists,
// float4/int4 register preload, branch-local early-break merge.
// blocks 128..199: build bf16 W0^T/W1^T into the dead xl region.
__global__ __launch_bounds__(64) void merge_kernel(
    const float* __restrict__ pk_d, const int* __restrict__ pk_i,
    int* __restrict__ edges, int* __restrict__ deg,
    const float* __restrict__ W0, const float* __restrict__ W1,
    unsigned short* __restrict__ wt)
{
    __shared__ float wtile[32][33];
    int tid = threadIdx.x;
    if (blockIdx.x >= 128) {             // ---- W transpose path
        int wid = blockIdx.x - 128;      // 0..71
        int mat = wid / 36, rem2 = wid % 36;
        int k0 = (rem2 / 6) * 32, n0 = (rem2 % 6) * 32;
        const float* W = mat ? W1 : W0;
#pragma unroll
        for (int p = 0; p < 4; ++p) {
            int idx = p * 64 + tid;
            int k = idx >> 3, n4 = (idx & 7) * 4;
            *(float4*)&wtile[k][n4] =
                *(const float4*)(W + (size_t)(k0 + k) * CF + n0 + n4);
        }
        __syncthreads();
#pragma unroll
        for (int p = 0; p < 4; ++p) {
            int idx = p * 64 + tid;
            int n = idx >> 3, k4 = (idx & 7) * 4;
            ushort4 h;
            h.x = f2bf(wtile[k4 + 0][n]); h.y = f2bf(wtile[k4 + 1][n]);
            h.z = f2bf(wtile[k4 + 2][n]); h.w = f2bf(wtile[k4 + 3][n]);
            *(ushort4*)(wt + (size_t)mat * 36864 + (size_t)(n0 + n) * CF + k0 + k4) = h;
        }
        return;
    }
    int q = blockIdx.x * 64 + tid;
    float td[KNN]; int ti[KNN];
#pragma unroll
    for (int j = 0; j < KNN; ++j) { td[j] = __builtin_inff(); ti[j] = -1; }
#pragma unroll
    for (int sb = 0; sb < 2; ++sb) {     // 2 batches of 4 splits, reg-preloaded
        float sd[4][KNN]; int si[4][KNN];
#pragma unroll
        for (int s2 = 0; s2 < 4; ++s2) {
            int s = sb * 4 + s2;         // compile-time (sb,s2 unrolled)
            const float* pd = pk_d + ((size_t)q * NSPL + s) * PKS;
            const int*   pp = pk_i + ((size_t)q * NSPL + s) * PKS;
            float4 d0 = *(const float4*)pd;
            float4 d1 = *(const float4*)(pd + 4);
            sd[s2][0] = d0.x; sd[s2][1] = d0.y; sd[s2][2] = d0.z; sd[s2][3] = d0.w;
            sd[s2][4] = d1.x; sd[s2][5] = d1.y; sd[s2][6] = d1.z; sd[s2][7] = d1.w;
            sd[s2][8] = pd[8];
            int4 i0 = *(const int4*)pp;
            int4 i1 = *(const int4*)(pp + 4);
            si[s2][0] = i0.x; si[s2][1] = i0.y; si[s2][2] = i0.z; si[s2][3] = i0.w;
            si[s2][4] = i1.x; si[s2][5] = i1.y; si[s2][6] = i1.z; si[s2][7] = i1.w;
            si[s2][8] = pp[8];
        }
#pragma unroll
        for (int s2 = 0; s2 < 4; ++s2) { // split order = index order (stable)
#pragma unroll
            for (int j0 = 0; j0 < KNN; ++j0) {
                float d = sd[s2][j0];
                if (!(d < td[KNN - 1])) break;   // sorted: rest can't insert
                td[KNN - 1] = d; ti[KNN - 1] = si[s2][j0];
#pragma unroll
                for (int j = KNN - 1; j > 0; --j) {
                    if (td[j] < td[j - 1]) {
                        float tf = td[j]; td[j] = td[j - 1]; td[j - 1] = tf;
                        int tn = ti[j]; ti[j] = ti[j - 1]; ti[j - 1] = tn;
                    }
                }
            }
        }
    }
#pragma unroll
    for (int j = 0; j < KNN; ++j) {
        int id = ti[j];                   // -1 <=> invalid (d == inf)
        edges[q * KNN + j] = id;
        if (id >= 0 && id != q) atomicAdd(&deg[id], 1);
    }
}

// ---------------------------------------------------------------- fused Tx1 + out GEMM (MFMA)
// One block per 16-row stripe (512 blocks). out = A0@W0 + A1@W1 + bias via
// mfma_f32_16x16x32_bf16, K=384 fused. R16/R18-proven form (present in both
// best-total runs). Gather: one uint4 (8 bf16 ch) per neighbor row.
// C/D (m89-verified): col=lane&15, row=(lane>>4)*4+reg. Wave w: n-tiles 3w..3w+2.
__global__ __launch_bounds__(256, 2) void out_kernel(
    const unsigned short* __restrict__ xh, const unsigned short* __restrict__ wt,
    const int* __restrict__ edges, const int* __restrict__ deg,
    const float* __restrict__ bias, float* __restrict__ out)
{
    __shared__ __align__(16) unsigned short A0s[16][200];  // xf rows  (padded)
    __shared__ __align__(16) unsigned short A1s[16][200];  // Tx1 rows (padded)
    __shared__ unsigned short Wts[2][CF][32];   // W^T k-slice (24576 B)
    __shared__ float coef_s[16][KNN];
    __shared__ int   nb_s[16][KNN];

    int r0 = blockIdx.x * 16;
    int tid = threadIdx.x;

    // stage xf rows (bf16 copy): 16 x 24 uint4 = 384
    for (int t = tid; t < 384; t += 256) {
        int i = t / 24, c8 = (t % 24) * 8;
        *(uint4*)&A0s[i][c8] = *(const uint4*)(xh + (size_t)(r0 + i) * CF + c8);
    }
    // coefficients: one (row, edge) per thread
    if (tid < 16 * KNN) {
        int i = tid / KNN, j = tid % KNN;
        int q = r0 + i;
        int id = edges[q * KNN + j];
        float cf = 0.0f; int s = q;
        if (id >= 0 && id != q) { cf = -disf(deg[id]) * disf(deg[q]); s = id; }
        coef_s[i][j] = cf; nb_s[i][j] = s;
    }
    __syncthreads();
    // gather Tx1 rows: role = (i, 8-ch block) -> 384 roles, uint4 per neighbor
    for (int e = tid; e < 16 * CF / 8; e += 256) {
        int i = e / 24, c8 = (e % 24) * 8;
        float a[8];
#pragma unroll
        for (int j = 0; j < 8; ++j) a[j] = 0.0f;
#pragma unroll
        for (int t = 0; t < KNN; ++t) {
            float cf = coef_s[i][t];
            uint4 v = *(const uint4*)(xh + (size_t)nb_s[i][t] * CF + c8);
            const unsigned short* pv = (const unsigned short*)&v;
#pragma unroll
            for (int j = 0; j < 8; ++j) a[j] = fmaf(cf, bf2f(pv[j]), a[j]);
        }
        uint4 hv;
        hv.x = (unsigned)f2bf(a[0]) | ((unsigned)f2bf(a[1]) << 16);
        hv.y = (unsigned)f2bf(a[2]) | ((unsigned)f2bf(a[3]) << 16);
        hv.z = (unsigned)f2bf(a[4]) | ((unsigned)f2bf(a[5]) << 16);
        hv.w = (unsigned)f2bf(a[6]) | ((unsigned)f2bf(a[7]) << 16);
        *(uint4*)&A1s[i][c8] = hv;
    }

    int lane = tid & 63, w = tid >> 6;
    int m = lane & 15;                   // A row / B col index
    int kq = (lane >> 4) * 8;            // k offset within 32-slice
    f32x4 acc[3];
#pragma unroll
    for (int t = 0; t < 3; ++t)
#pragma unroll
        for (int r = 0; r < 4; ++r) acc[t][r] = 0.0f;

    for (int kt = 0; kt < 6; ++kt) {     // K=192 in 32-slices, both mats fused
        __syncthreads();                 // kt=0: A1s ready; else Wts consumed
#pragma unroll
        for (int p = 0; p < 6; ++p) {    // stage Wts: 1536 uint4
            int f = p * 256 + tid;
            int mat = f / 768, n = (f % 768) / 4, k16 = (f % 4) * 8;
            *(uint4*)&Wts[mat][n][k16] =
                *(const uint4*)(wt + (size_t)mat * 36864 + (size_t)n * CF + kt * 32 + k16);
        }
        __syncthreads();
        v8bf a0 = *(const v8bf*)&A0s[m][kt * 32 + kq];
        v8bf a1 = *(const v8bf*)&A1s[m][kt * 32 + kq];
#pragma unroll
        for (int t3 = 0; t3 < 3; ++t3) {
            int n0 = w * 48 + t3 * 16;
            v8bf w0 = *(const v8bf*)&Wts[0][n0 + m][kq];
            v8bf w1 = *(const v8bf*)&Wts[1][n0 + m][kq];
            acc[t3] = __builtin_amdgcn_mfma_f32_16x16x32_bf16(a0, w0, acc[t3], 0, 0, 0);
            acc[t3] = __builtin_amdgcn_mfma_f32_16x16x32_bf16(a1, w1, acc[t3], 0, 0, 0);
        }
    }

    int col = lane & 15, rb = (lane >> 4) * 4;
#pragma unroll
    for (int t3 = 0; t3 < 3; ++t3) {
        int n0 = w * 48 + t3 * 16;
        float bv = bias[n0 + col];
#pragma unroll
        for (int r = 0; r < 4; ++r)
            out[(size_t)(r0 + rb + r) * CF + n0 + col] = acc[t3][r] + bv;
    }
}

// ---------------------------------------------------------------- launch
extern "C" void kernel_launch(void* const* d_in, const int* in_sizes, int n_in,
                              void* d_out, int out_size, void* d_ws, size_t ws_size,
                              hipStream_t stream)
{
    const float* x    = (const float*)d_in[0];
    const float* W0   = (const float*)d_in[1];
    const float* W1   = (const float*)d_in[2];
    const float* bias = (const float*)d_in[3];
    float* out = (float*)d_out;

    // Workspace: 6,651,904 B (known-safe total).
    char* ws = (char*)d_ws;
    unsigned short* xh = (unsigned short*)ws; ws += (size_t)NN * CF * 2;  // 3,145,728
    unsigned short* xl = (unsigned short*)ws; ws += (size_t)NN * CF * 2;  // 3,145,728  (contiguous after xh — knn relies on this)
    float* sq    = (float*)ws;  ws += (size_t)NN * 4;        //    32,768
    int*   deg   = (int*)ws;    ws += (size_t)NN * 4;        //    32,768
    int*   edges = (int*)ws;    ws += (size_t)NN * KNN * 4;  //   294,912

    // xl is dead after knn -> reuse its space for bf16 W0^T/W1^T (147 KB).
    unsigned short* wt = xl;

    // Partial top-k lists live in d_out (exactly 6.29 MB with PKS=12); d_out
    // is fully overwritten by out_kernel afterwards, every call.
    float* pk_d = out;                                        // NN*NSPL*PKS fl
    int*   pk_i = (int*)(out + (size_t)NN * NSPL * PKS);      // NN*NSPL*PKS int

    hipLaunchKernelGGL(transpose_kernel, dim3(8, 16), dim3(256), 0, stream,
                       x, xh, xl, sq, deg);
    hipLaunchKernelGGL(knn_kernel, dim3(576), dim3(256), 0, stream,
                       xh, xl, sq, pk_d, pk_i);
    hipLaunchKernelGGL(merge_kernel, dim3(200), dim3(64), 0, stream,
                       pk_d, pk_i, edges, deg, W0, W1, wt);
    hipLaunchKernelGGL(out_kernel, dim3(512), dim3(256), 0, stream,
                       xh, wt, edges, deg, bias, out);
}